// Round 7
// baseline (2956.219 us; speedup 1.0000x reference)
//
#include <hip/hip_runtime.h>
#include <hip/hip_bf16.h>

// ---------------------------------------------------------------------------
// 2-layer LSTM, B=64 T=256 N=512 H=1024.
// R7: spatial layer split. Per 128-WG pod: 64 WGs = layer0 (tight recurrent
// loop, one publish->poll hop per epoch), 64 WGs = layer1 (runs one hop
// behind, no backpressure on layer0). Write-once h rings (cached consumer
// loads), uncached publishes, per-(pod,layer) arrival counters.
// ---------------------------------------------------------------------------

#define T_ 256
#define B_ 64
#define N_ 512
#define H_ 1024
#define FH_ 4096
#define NWG_SEQ 256
#define BH_ (B_ * H_)

typedef _Float16 f16;
typedef _Float16 f16x4 __attribute__((ext_vector_type(4)));
typedef _Float16 f16x8 __attribute__((ext_vector_type(8)));
typedef float f32x4 __attribute__((ext_vector_type(4)));
typedef unsigned long long ull;

__device__ __forceinline__ float sigf(float x) { return 1.f / (1.f + __expf(-x)); }
__device__ __forceinline__ float tanhf_fast(float x) { return 1.f - 2.f / (__expf(2.f * x) + 1.f); }

__device__ __forceinline__ void st_u64g(ull* p, ull v) {
  __hip_atomic_store(p, v, __ATOMIC_RELAXED, __HIP_MEMORY_SCOPE_AGENT);
}
__device__ __forceinline__ f16x8 ld_b128_nc(const f16* p) {
  f16x8 r;
  asm volatile("global_load_dwordx4 %0, %1, off sc0 sc1" : "=v"(r) : "v"(p));
  return r;
}
template <bool CACHED>
__device__ __forceinline__ f16x8 ldf(const f16* p) {
  if constexpr (CACHED) return *(const f16x8*)p;
  else return ld_b128_nc(p);
}

// ---------------------------------------------------------------------------
// init / convert kernel
// ---------------------------------------------------------------------------
__global__ __launch_bounds__(256) void init_all(
    const float* __restrict__ x, const float* __restrict__ h,
    const float* __restrict__ Wih0, const float* __restrict__ bih0, const float* __restrict__ bhh0,
    const float* __restrict__ Whh0, const float* __restrict__ Wih1, const float* __restrict__ Whh1,
    const float* __restrict__ bih1, const float* __restrict__ bhh1,
    f16* __restrict__ xT, f16* __restrict__ wih0, f16* __restrict__ whh0,
    f16* __restrict__ wih1, f16* __restrict__ whh1,
    float* __restrict__ bias0, float* __restrict__ bias1,
    f16* __restrict__ hinit, unsigned* __restrict__ cnt)
{
  const int stride = gridDim.x * blockDim.x;
  const int t0 = blockIdx.x * blockDim.x + threadIdx.x;

  for (int i = t0; i < T_ * B_ * N_; i += stride) {
    int n = i & (N_ - 1);
    int tb = i >> 9;
    int b = tb & (B_ - 1);
    int t = tb >> 6;
    xT[i] = (f16)x[((size_t)b * T_ + t) * N_ + n];
  }
  for (int i = t0; i < FH_ * N_; i += stride) wih0[i] = (f16)Wih0[i];
  for (int i = t0; i < FH_ * H_; i += stride) {
    whh0[i] = (f16)Whh0[i];
    wih1[i] = (f16)Wih1[i];
    whh1[i] = (f16)Whh1[i];
  }
  for (int i = t0; i < FH_; i += stride) {
    bias0[i] = bih0[i] + bhh0[i];
    bias1[i] = bih1[i] + bhh1[i];
  }
  for (int i = t0; i < 2 * BH_; i += stride) hinit[i] = (f16)h[i];
  if (t0 < 2048) cnt[t0] = 0u;
}

// ---------------------------------------------------------------------------
// GEMM: pre0T[t][col][b] = (xT @ wih0^T + bias0), stored f16 TRANSPOSED.
// ---------------------------------------------------------------------------
__global__ __launch_bounds__(256) void gemm_pre0(
    const f16* __restrict__ xT, const f16* __restrict__ wih0,
    const float* __restrict__ bias0, f16* __restrict__ pre0T)
{
  const int wid = threadIdx.x >> 6;
  const int lane = threadIdx.x & 63;
  const int lr = lane & 15;
  const int lkq = (lane >> 4) << 3;
  const int lrq = (lane >> 4) << 2;

  const int mt = blockIdx.x & 255;
  const int ct = (blockIdx.x >> 8) * 4 + wid;
  const int row0 = mt * 64, col0 = ct * 64;

  f32x4 acc[4][4] = {};
  const f16* Abase = xT + (size_t)row0 * N_;

  #pragma unroll 2
  for (int kk = 0; kk < N_ / 32; ++kk) {
    const int k = kk * 32 + lkq;
    f16x8 a[4], b[4];
    #pragma unroll
    for (int r = 0; r < 4; ++r)
      a[r] = *(const f16x8*)(Abase + (size_t)(r * 16 + lr) * N_ + k);
    #pragma unroll
    for (int cf = 0; cf < 4; ++cf)
      b[cf] = *(const f16x8*)(wih0 + (size_t)(col0 + cf * 16 + lr) * N_ + k);
    #pragma unroll
    for (int r = 0; r < 4; ++r)
      #pragma unroll
      for (int cf = 0; cf < 4; ++cf)
        acc[r][cf] = __builtin_amdgcn_mfma_f32_16x16x32_f16(a[r], b[cf], acc[r][cf], 0, 0, 0);
  }

  #pragma unroll
  for (int r = 0; r < 4; ++r) {
    #pragma unroll
    for (int cf = 0; cf < 4; ++cf) {
      const int col = col0 + cf * 16 + lr;
      const float bv = bias0[col];
      f16x4 pv;
      #pragma unroll
      for (int ri = 0; ri < 4; ++ri) pv[ri] = (f16)(acc[r][cf][ri] + bv);
      *(f16x4*)(pre0T + ((size_t)mt * FH_ + col) * 64 + r * 16 + lrq) = pv;
    }
  }
}

// ---------------------------------------------------------------------------
// Persistent layer-split dataflow kernel. 256 WGs x 256 threads (1 WG/CU).
// pod = wg>>7 (batch rows pod*32..+31). slot = wg&127.
// role = slot>>6 (0 = layer0, 1 = layer1). us = (slot&63)*16 (units).
// cnt layout: cnt0 = cnt + pod*512 (layer0 arrivals per epoch, target 64),
//             cnt1 = cnt + 1024 + pod*512.
// ---------------------------------------------------------------------------
template <bool DEEP>
__global__ __launch_bounds__(256, 1) void lstm_seq(
    const f16* __restrict__ pre0T, const f16* __restrict__ whh0,
    const f16* __restrict__ wih1, const f16* __restrict__ whh1,
    const float* __restrict__ bias1, const f16* __restrict__ hinit,
    const float* __restrict__ cin,
    f16* __restrict__ h0r, f16* __restrict__ h1r,
    float* __restrict__ out, unsigned* __restrict__ cnt)
{
  __shared__ __align__(16) float exc[4][4][32][17];   // [p][gate][row][unit]
  __shared__ __align__(16) f16 smH[32][16];

  const int tid = threadIdx.x;
  const int p = tid >> 6;
  const int lane = tid & 63;
  const int lr = lane & 15;
  const int lq = lane >> 4;
  const int lkq = lq << 3;
  const int lrq = lq << 2;

  const int wg = blockIdx.x;
  const int pod = wg >> 7;
  const int slot = wg & 127;
  const int role = slot >> 6;
  const int us = (slot & 63) << 4;   // unit base (16 units per WG)
  const int rs = pod << 5;

  unsigned* cnt0 = cnt + pod * 512;
  unsigned* cnt1 = cnt + 1024 + pod * 512;

  // per-thread cells: (row rc0, unit uc) and (row rc0+16, unit uc)
  const int rc0 = tid >> 4;
  const int uc = tid & 15;
  const int rc1 = rc0 + 16;
  const size_t cellA = (size_t)(rs + rc0) * H_ + us + uc;
  const size_t cellB = (size_t)(rs + rc1) * H_ + us + uc;

  float* outh = out + (size_t)B_ * T_ * H_;
  float* outc = outh + 2 * BH_;

  auto rt = [&](int t) -> size_t { return DEEP ? (size_t)t : (size_t)(t & 7); };
  auto pollw = [&](unsigned* w2) {
    if (tid == 0) {
      while (__hip_atomic_load(w2, __ATOMIC_RELAXED, __HIP_MEMORY_SCOPE_AGENT) < 64u)
        __builtin_amdgcn_s_sleep(1);
    }
  };

  if (role == 0) {
    // =========================== LAYER 0 =================================
    f16x8 w0[4][8];
    #pragma unroll
    for (int cf = 0; cf < 4; ++cf)
      #pragma unroll
      for (int j = 0; j < 8; ++j)
        w0[cf][j] = *(const f16x8*)(whh0 + (size_t)(cf * H_ + us + lr) * H_ + (p * 8 + j) * 32 + lkq);

    float cA = cin[cellA], cB = cin[cellB];

    for (int e = 0; e < T_; ++e) {
      // pre0 additive terms (cached, before poll)
      float pfA[4], pfB[4];
      #pragma unroll
      for (int g = 0; g < 4; ++g) {
        pfA[g] = (float)pre0T[((size_t)e * FH_ + g * H_ + us + uc) * 64 + rs + rc0];
        pfB[g] = (float)pre0T[((size_t)e * FH_ + g * H_ + us + uc) * 64 + rs + rc1];
      }

      if (e > 0) pollw(&cnt0[e - 1]);
      if (!DEEP && e >= 8) pollw(&cnt1[e - 8]);   // ring0 slot-reuse safety
      __syncthreads();

      const f16* src = ((e == 0) ? hinit : h0r + rt(e - 1) * BH_) + (size_t)rs * H_;
      f16x8 af0[8], af1[8];
      #pragma unroll
      for (int j = 0; j < 8; ++j) {
        const int k = (p * 8 + j) * 32 + lkq;
        af0[j] = ldf<DEEP>(src + (size_t)lr * H_ + k);
        af1[j] = ldf<DEEP>(src + (size_t)(16 + lr) * H_ + k);
      }
      if (!DEEP) {
        asm volatile("s_waitcnt vmcnt(0)" ::: "memory");
        __builtin_amdgcn_sched_barrier(0);
      }

      f32x4 acc[4][2] = {};
      #pragma unroll
      for (int j = 0; j < 8; ++j)
        #pragma unroll
        for (int cf = 0; cf < 4; ++cf) {
          acc[cf][0] = __builtin_amdgcn_mfma_f32_16x16x32_f16(af0[j], w0[cf][j], acc[cf][0], 0, 0, 0);
          acc[cf][1] = __builtin_amdgcn_mfma_f32_16x16x32_f16(af1[j], w0[cf][j], acc[cf][1], 0, 0, 0);
        }

      #pragma unroll
      for (int cf = 0; cf < 4; ++cf)
        #pragma unroll
        for (int rf = 0; rf < 2; ++rf)
          #pragma unroll
          for (int ri = 0; ri < 4; ++ri)
            exc[p][cf][rf * 16 + lrq + ri][lr] = acc[cf][rf][ri];
      __syncthreads();

      float gvA[4], gvB[4];
      #pragma unroll
      for (int g = 0; g < 4; ++g) {
        gvA[g] = exc[0][g][rc0][uc] + exc[1][g][rc0][uc]
               + exc[2][g][rc0][uc] + exc[3][g][rc0][uc] + pfA[g];
        gvB[g] = exc[0][g][rc1][uc] + exc[1][g][rc1][uc]
               + exc[2][g][rc1][uc] + exc[3][g][rc1][uc] + pfB[g];
      }
      const float cnA = sigf(gvA[1]) * cA + sigf(gvA[0]) * tanhf_fast(gvA[2]);
      const float hnA = sigf(gvA[3]) * tanhf_fast(cnA);
      const float cnB = sigf(gvB[1]) * cB + sigf(gvB[0]) * tanhf_fast(gvB[2]);
      const float hnB = sigf(gvB[3]) * tanhf_fast(cnB);
      cA = cnA; cB = cnB;
      smH[rc0][uc] = (f16)hnA;
      smH[rc1][uc] = (f16)hnB;
      __syncthreads();

      if (p == 0) {
        const int row = lane >> 1, u8 = (lane & 1) * 8;
        f16* dst = h0r + rt(e) * BH_ + (size_t)(rs + row) * H_ + us + u8;
        st_u64g((ull*)dst, *(const ull*)&smH[row][u8]);
        st_u64g((ull*)(dst + 4), *(const ull*)&smH[row][u8 + 4]);
      }
      asm volatile("s_waitcnt vmcnt(0)" ::: "memory");
      __syncthreads();
      if (tid == 0)
        (void)__hip_atomic_fetch_add(&cnt0[e], 1u, __ATOMIC_RELAXED, __HIP_MEMORY_SCOPE_AGENT);

      if (e == T_ - 1) {
        outh[cellA] = hnA; outc[cellA] = cnA;
        outh[cellB] = hnB; outc[cellB] = cnB;
      }
    }
  } else {
    // =========================== LAYER 1 =================================
    f16x8 wa[4][8], wb[4][8];
    #pragma unroll
    for (int cf = 0; cf < 4; ++cf)
      #pragma unroll
      for (int j = 0; j < 8; ++j) {
        const size_t wr = (size_t)(cf * H_ + us + lr) * H_ + (p * 8 + j) * 32 + lkq;
        wa[cf][j] = *(const f16x8*)(wih1 + wr);
        wb[cf][j] = *(const f16x8*)(whh1 + wr);
      }

    float cA = cin[BH_ + cellA], cB = cin[BH_ + cellB];
    float b1[4];
    #pragma unroll
    for (int g = 0; g < 4; ++g) b1[g] = bias1[g * H_ + us + uc];

    for (int e = 0; e < T_; ++e) {
      pollw(&cnt0[e]);                 // h0[e] ready
      if (e > 0) pollw(&cnt1[e - 1]);  // h1[e-1] ready
      __syncthreads();

      const f16* s0 = h0r + rt(e) * BH_ + (size_t)rs * H_;
      const f16* s1 = ((e == 0) ? hinit + BH_ : h1r + rt(e - 1) * BH_) + (size_t)rs * H_;
      f16x8 a0[8], a1[8], d0[8], d1[8];
      #pragma unroll
      for (int j = 0; j < 8; ++j) {
        const int k = (p * 8 + j) * 32 + lkq;
        a0[j] = ldf<DEEP>(s0 + (size_t)lr * H_ + k);
        a1[j] = ldf<DEEP>(s0 + (size_t)(16 + lr) * H_ + k);
        d0[j] = ldf<DEEP>(s1 + (size_t)lr * H_ + k);
        d1[j] = ldf<DEEP>(s1 + (size_t)(16 + lr) * H_ + k);
      }
      if (!DEEP) {
        asm volatile("s_waitcnt vmcnt(0)" ::: "memory");
        __builtin_amdgcn_sched_barrier(0);
      }

      f32x4 acc[4][2] = {};
      #pragma unroll
      for (int j = 0; j < 8; ++j)
        #pragma unroll
        for (int cf = 0; cf < 4; ++cf) {
          acc[cf][0] = __builtin_amdgcn_mfma_f32_16x16x32_f16(a0[j], wa[cf][j], acc[cf][0], 0, 0, 0);
          acc[cf][1] = __builtin_amdgcn_mfma_f32_16x16x32_f16(a1[j], wa[cf][j], acc[cf][1], 0, 0, 0);
        }
      #pragma unroll
      for (int j = 0; j < 8; ++j)
        #pragma unroll
        for (int cf = 0; cf < 4; ++cf) {
          acc[cf][0] = __builtin_amdgcn_mfma_f32_16x16x32_f16(d0[j], wb[cf][j], acc[cf][0], 0, 0, 0);
          acc[cf][1] = __builtin_amdgcn_mfma_f32_16x16x32_f16(d1[j], wb[cf][j], acc[cf][1], 0, 0, 0);
        }

      #pragma unroll
      for (int cf = 0; cf < 4; ++cf)
        #pragma unroll
        for (int rf = 0; rf < 2; ++rf)
          #pragma unroll
          for (int ri = 0; ri < 4; ++ri)
            exc[p][cf][rf * 16 + lrq + ri][lr] = acc[cf][rf][ri];
      __syncthreads();

      float gvA[4], gvB[4];
      #pragma unroll
      for (int g = 0; g < 4; ++g) {
        gvA[g] = exc[0][g][rc0][uc] + exc[1][g][rc0][uc]
               + exc[2][g][rc0][uc] + exc[3][g][rc0][uc] + b1[g];
        gvB[g] = exc[0][g][rc1][uc] + exc[1][g][rc1][uc]
               + exc[2][g][rc1][uc] + exc[3][g][rc1][uc] + b1[g];
      }
      const float cnA = sigf(gvA[1]) * cA + sigf(gvA[0]) * tanhf_fast(gvA[2]);
      const float hnA = sigf(gvA[3]) * tanhf_fast(cnA);
      const float cnB = sigf(gvB[1]) * cB + sigf(gvB[0]) * tanhf_fast(gvB[2]);
      const float hnB = sigf(gvB[3]) * tanhf_fast(cnB);
      cA = cnA; cB = cnB;
      smH[rc0][uc] = (f16)hnA;
      smH[rc1][uc] = (f16)hnB;
      __syncthreads();

      if (p == 0) {
        const int row = lane >> 1, u8 = (lane & 1) * 8;
        f16* dst = h1r + rt(e) * BH_ + (size_t)(rs + row) * H_ + us + u8;
        st_u64g((ull*)dst, *(const ull*)&smH[row][u8]);
        st_u64g((ull*)(dst + 4), *(const ull*)&smH[row][u8 + 4]);
      }
      asm volatile("s_waitcnt vmcnt(0)" ::: "memory");
      __syncthreads();
      if (tid == 0)
        (void)__hip_atomic_fetch_add(&cnt1[e], 1u, __ATOMIC_RELAXED, __HIP_MEMORY_SCOPE_AGENT);

      // out writes AFTER publish+flag (off the critical path)
      out[(size_t)(rs + rc0) * (T_ * H_) + (size_t)e * H_ + us + uc] = hnA;
      out[(size_t)(rs + rc1) * (T_ * H_) + (size_t)e * H_ + us + uc] = hnB;
      if (e == T_ - 1) {
        outh[BH_ + cellA] = hnA; outc[BH_ + cellA] = cnA;
        outh[BH_ + cellB] = hnB; outc[BH_ + cellB] = cnB;
      }
    }
  }
}

// ---------------------------------------------------------------------------
extern "C" void kernel_launch(void* const* d_in, const int* in_sizes, int n_in,
                              void* d_out, int out_size, void* d_ws, size_t ws_size,
                              hipStream_t stream)
{
  const float* x    = (const float*)d_in[0];
  const float* h    = (const float*)d_in[1];
  const float* c    = (const float*)d_in[2];
  const float* Wih0 = (const float*)d_in[3];
  const float* Whh0 = (const float*)d_in[4];
  const float* bih0 = (const float*)d_in[5];
  const float* bhh0 = (const float*)d_in[6];
  const float* Wih1 = (const float*)d_in[7];
  const float* Whh1 = (const float*)d_in[8];
  const float* bih1 = (const float*)d_in[9];
  const float* bhh1 = (const float*)d_in[10];

  char* w = (char*)d_ws;
  size_t off = 0;
  auto carve = [&](size_t bytes) -> char* {
    char* ptr = w + off;
    off = (off + bytes + 255) & ~(size_t)255;
    return ptr;
  };
  f16*   pre0T = (f16*)  carve((size_t)T_ * B_ * FH_ * 2);
  f16*   xT    = (f16*)  carve((size_t)T_ * B_ * N_ * 2);
  f16*   wih0  = (f16*)  carve((size_t)FH_ * N_ * 2);
  f16*   whh0  = (f16*)  carve((size_t)FH_ * H_ * 2);
  f16*   wih1  = (f16*)  carve((size_t)FH_ * H_ * 2);
  f16*   whh1  = (f16*)  carve((size_t)FH_ * H_ * 2);
  float* bias0 = (float*)carve((size_t)FH_ * 4);
  float* bias1 = (float*)carve((size_t)FH_ * 4);
  f16*   hinit = (f16*)  carve((size_t)2 * BH_ * 2);
  f16*   h0s   = (f16*)  carve((size_t)8 * BH_ * 2);   // shallow fallback rings
  f16*   h1s   = (f16*)  carve((size_t)8 * BH_ * 2);
  unsigned* cnt = (unsigned*)carve(2048 * 4);
  const size_t base_end = off;
  f16*   h0ring = (f16*) carve((size_t)T_ * BH_ * 2);  // deep write-once rings
  f16*   h1ring = (f16*) carve((size_t)T_ * BH_ * 2);
  const bool deep = (off <= ws_size);
  if (base_end > ws_size) return;

  init_all<<<2048, 256, 0, stream>>>(x, h, Wih0, bih0, bhh0, Whh0, Wih1, Whh1, bih1, bhh1,
                                     xT, wih0, whh0, wih1, whh1, bias0, bias1, hinit, cnt);
  gemm_pre0<<<4096, 256, 0, stream>>>(xT, wih0, bias0, pre0T);
  if (deep)
    lstm_seq<true><<<NWG_SEQ, 256, 0, stream>>>(pre0T, whh0, wih1, whh1, bias1, hinit,
                                                (const float*)c, h0ring, h1ring,
                                                (float*)d_out, cnt);
  else
    lstm_seq<false><<<NWG_SEQ, 256, 0, stream>>>(pre0T, whh0, wih1, whh1, bias1, hinit,
                                                 (const float*)c, h0s, h1s,
                                                 (float*)d_out, cnt);
}

// Round 8
// 2063.070 us; speedup vs baseline: 1.4329x; 1.4329x over previous
//
#include <hip/hip_runtime.h>
#include <hip/hip_bf16.h>

// ---------------------------------------------------------------------------
// 2-layer LSTM, B=64 T=256 N=512 H=1024.
// R8: merged epoch (R5 body) + cached write-once rings (R6) + per-WG flag
// STORES (no atomic RMW fan-in). One publish+drain+flag hop per epoch.
// Natural lockstep coupling (no sprint). Weights pinned in VGPRs.
// ---------------------------------------------------------------------------

#define T_ 256
#define B_ 64
#define N_ 512
#define H_ 1024
#define FH_ 4096
#define NWG_SEQ 256
#define BH_ (B_ * H_)

typedef _Float16 f16;
typedef _Float16 f16x4 __attribute__((ext_vector_type(4)));
typedef _Float16 f16x8 __attribute__((ext_vector_type(8)));
typedef float f32x4 __attribute__((ext_vector_type(4)));
typedef unsigned long long ull;

template <bool V> struct BC { static constexpr bool value = V; };

__device__ __forceinline__ float sigf(float x) { return 1.f / (1.f + __expf(-x)); }
__device__ __forceinline__ float tanhf_fast(float x) { return 1.f - 2.f / (__expf(2.f * x) + 1.f); }

// uncached (bypass L1/L2, MALL-coherent) accessors
__device__ __forceinline__ void st_u64g(ull* p, ull v) {
  __hip_atomic_store(p, v, __ATOMIC_RELAXED, __HIP_MEMORY_SCOPE_AGENT);
}
__device__ __forceinline__ void st_u32g(unsigned* p, unsigned v) {
  __hip_atomic_store(p, v, __ATOMIC_RELAXED, __HIP_MEMORY_SCOPE_AGENT);
}
__device__ __forceinline__ ull ld_u64g(const ull* p) {
  return __hip_atomic_load(p, __ATOMIC_RELAXED, __HIP_MEMORY_SCOPE_AGENT);
}
__device__ __forceinline__ f16x8 ld_b128_nc(const f16* p) {
  f16x8 r;
  asm volatile("global_load_dwordx4 %0, %1, off sc0 sc1" : "=v"(r) : "v"(p));
  return r;
}
template <bool CACHED>
__device__ __forceinline__ f16x8 ldf(const f16* p) {
  if constexpr (CACHED) return *(const f16x8*)p;
  else return ld_b128_nc(p);
}

// ---------------------------------------------------------------------------
// init / convert kernel
// ---------------------------------------------------------------------------
__global__ __launch_bounds__(256) void init_all(
    const float* __restrict__ x, const float* __restrict__ h,
    const float* __restrict__ Wih0, const float* __restrict__ bih0, const float* __restrict__ bhh0,
    const float* __restrict__ Whh0, const float* __restrict__ Wih1, const float* __restrict__ Whh1,
    const float* __restrict__ bih1, const float* __restrict__ bhh1,
    f16* __restrict__ xT, f16* __restrict__ wih0, f16* __restrict__ whh0,
    f16* __restrict__ wih1, f16* __restrict__ whh1,
    float* __restrict__ bias0, float* __restrict__ bias1,
    f16* __restrict__ hinit, unsigned* __restrict__ flags)
{
  const int stride = gridDim.x * blockDim.x;
  const int t0 = blockIdx.x * blockDim.x + threadIdx.x;

  for (int i = t0; i < T_ * B_ * N_; i += stride) {
    int n = i & (N_ - 1);
    int tb = i >> 9;
    int b = tb & (B_ - 1);
    int t = tb >> 6;
    xT[i] = (f16)x[((size_t)b * T_ + t) * N_ + n];
  }
  for (int i = t0; i < FH_ * N_; i += stride) wih0[i] = (f16)Wih0[i];
  for (int i = t0; i < FH_ * H_; i += stride) {
    whh0[i] = (f16)Whh0[i];
    wih1[i] = (f16)Wih1[i];
    whh1[i] = (f16)Whh1[i];
  }
  for (int i = t0; i < FH_; i += stride) {
    bias0[i] = bih0[i] + bhh0[i];
    bias1[i] = bih1[i] + bhh1[i];
  }
  for (int i = t0; i < 2 * BH_; i += stride) hinit[i] = (f16)h[i];
  if (t0 < 256) flags[t0] = 0u;
}

// ---------------------------------------------------------------------------
// GEMM: pre0T[t][col][b] = (xT @ wih0^T + bias0), stored f16 TRANSPOSED.
// ---------------------------------------------------------------------------
__global__ __launch_bounds__(256) void gemm_pre0(
    const f16* __restrict__ xT, const f16* __restrict__ wih0,
    const float* __restrict__ bias0, f16* __restrict__ pre0T)
{
  const int wid = threadIdx.x >> 6;
  const int lane = threadIdx.x & 63;
  const int lr = lane & 15;
  const int lkq = (lane >> 4) << 3;
  const int lrq = (lane >> 4) << 2;

  const int mt = blockIdx.x & 255;
  const int ct = (blockIdx.x >> 8) * 4 + wid;
  const int row0 = mt * 64, col0 = ct * 64;

  f32x4 acc[4][4] = {};
  const f16* Abase = xT + (size_t)row0 * N_;

  #pragma unroll 2
  for (int kk = 0; kk < N_ / 32; ++kk) {
    const int k = kk * 32 + lkq;
    f16x8 a[4], b[4];
    #pragma unroll
    for (int r = 0; r < 4; ++r)
      a[r] = *(const f16x8*)(Abase + (size_t)(r * 16 + lr) * N_ + k);
    #pragma unroll
    for (int cf = 0; cf < 4; ++cf)
      b[cf] = *(const f16x8*)(wih0 + (size_t)(col0 + cf * 16 + lr) * N_ + k);
    #pragma unroll
    for (int r = 0; r < 4; ++r)
      #pragma unroll
      for (int cf = 0; cf < 4; ++cf)
        acc[r][cf] = __builtin_amdgcn_mfma_f32_16x16x32_f16(a[r], b[cf], acc[r][cf], 0, 0, 0);
  }

  #pragma unroll
  for (int r = 0; r < 4; ++r) {
    #pragma unroll
    for (int cf = 0; cf < 4; ++cf) {
      const int col = col0 + cf * 16 + lr;
      const float bv = bias0[col];
      f16x4 pv;
      #pragma unroll
      for (int ri = 0; ri < 4; ++ri) pv[ri] = (f16)(acc[r][cf][ri] + bv);
      *(f16x4*)(pre0T + ((size_t)mt * FH_ + col) * 64 + r * 16 + lrq) = pv;
    }
  }
}

// ---------------------------------------------------------------------------
// Persistent merged dataflow kernel. 256 WGs x 256 threads (1 WG/CU).
// Pod P = 128 WGs, batch rows P*32..P*32+31. WG owns 8 units of each gate.
// Epoch e: layer0 step e + layer1 step e-1. One publish+drain+flag per epoch.
// flags[pod*128 + slot] = number of completed epochs by that WG.
// ---------------------------------------------------------------------------
template <bool DEEP>
__global__ __launch_bounds__(256, 1) void lstm_seq(
    const f16* __restrict__ pre0T, const f16* __restrict__ whh0,
    const f16* __restrict__ wih1, const f16* __restrict__ whh1,
    const float* __restrict__ bias1, const f16* __restrict__ hinit,
    const float* __restrict__ cin,
    f16* __restrict__ h0r, f16* __restrict__ h1r,
    float* __restrict__ out, unsigned* __restrict__ flags)
{
  __shared__ __align__(16) float exc[2][4][32][33];   // partial-sum exchange
  __shared__ __align__(16) f16 smH[2][32][8];         // packed h outputs

  const int tid = threadIdx.x;
  const int p = tid >> 6;          // wave = K-quarter
  const int lane = tid & 63;
  const int lr = lane & 15;
  const int lq = lane >> 4;
  const int lkq = lq << 3;
  const int lrq = lq << 2;

  const int wg = blockIdx.x;
  const int pod = wg >> 7;         // 0: rows 0..31, 1: rows 32..63
  const int slot = wg & 127;
  const int rs = pod << 5;
  const int ub = slot << 3;        // unit base: 8 units per gate
  unsigned* podflags = flags + (pod << 7);

  auto rt = [&](int t) -> size_t { return DEEP ? (size_t)t : (size_t)(t & 7); };

  // ---- preload weight fragments into registers (48 x f16x8) ----
  f16x8 l0w[2][8], l1aw[2][8], l1bw[2][8];
  #pragma unroll
  for (int cf = 0; cf < 2; ++cf) {
    const size_t wr = (size_t)((2 * cf + (lr >> 3)) * H_ + ub + (lr & 7)) * H_;
    #pragma unroll
    for (int j = 0; j < 8; ++j) {
      const int k = (p * 8 + j) * 32 + lkq;
      l0w[cf][j]  = *(const f16x8*)(whh0 + wr + k);
      l1aw[cf][j] = *(const f16x8*)(wih1 + wr + k);
      l1bw[cf][j] = *(const f16x8*)(whh1 + wr + k);
    }
  }

  // ---- per-thread cell state ----
  const int crow = tid & 31;
  const int cu = tid >> 5;
  const size_t cell = (size_t)(rs + crow) * H_ + ub + cu;
  float c0 = cin[cell];
  float c1 = cin[(size_t)BH_ + cell];
  float b1v[4];
  #pragma unroll
  for (int g = 0; g < 4; ++g) b1v[g] = bias1[g * H_ + ub + cu];

  float* outh = out + (size_t)B_ * T_ * H_;
  float* outc = outh + 2 * BH_;

  auto body = [&](auto A0c, auto A1c, int e) {
    constexpr bool A0 = decltype(A0c)::value;
    constexpr bool A1 = decltype(A1c)::value;

    // pre0 additive term: cached, issued before the poll
    float pf[4];
    if (A0) {
      #pragma unroll
      for (int g = 0; g < 4; ++g)
        pf[g] = (float)pre0T[((size_t)e * FH_ + g * H_ + ub + cu) * 64 + rs + crow];
    }

    // poll: all 128 pod flags >= e (wave0, wide uncached u64 loads)
    if (e > 0 && p == 0) {
      const ull* fp = (const ull*)podflags;
      for (;;) {
        ull v = ld_u64g(&fp[lane]);
        const bool ok = ((unsigned)v >= (unsigned)e) && ((unsigned)(v >> 32) >= (unsigned)e);
        if (__ballot(ok) == ~0ull) break;
        __builtin_amdgcn_s_sleep(1);
      }
    }
    __syncthreads();

    // ---- fragment loads (cached when DEEP: write-once addresses) ----
    const f16* h0s = ((e == 0) ? hinit : h0r + rt(e - 1) * BH_) + (size_t)rs * H_;
    const f16* h1s = A1 ? (((e == 1) ? hinit + BH_ : h1r + rt(e - 2) * BH_) + (size_t)rs * H_)
                        : (const f16*)nullptr;
    f16x8 a0v[8], a1v[8], c0v[8], c1v[8];
    #pragma unroll
    for (int j = 0; j < 8; ++j) {
      const int k = (p * 8 + j) * 32 + lkq;
      a0v[j] = ldf<DEEP>(h0s + (size_t)lr * H_ + k);
      a1v[j] = ldf<DEEP>(h0s + (size_t)(16 + lr) * H_ + k);
    }
    if (A1) {
      #pragma unroll
      for (int j = 0; j < 8; ++j) {
        const int k = (p * 8 + j) * 32 + lkq;
        c0v[j] = ldf<DEEP>(h1s + (size_t)lr * H_ + k);
        c1v[j] = ldf<DEEP>(h1s + (size_t)(16 + lr) * H_ + k);
      }
    }
    if (!DEEP) {
      asm volatile("s_waitcnt vmcnt(0)" ::: "memory");
      __builtin_amdgcn_sched_barrier(0);
    }

    // ---- MFMAs: layer0 (whh0) + layer1 (wih1 on h0, whh1 on h1) ----
    f32x4 acc0[2][2] = {};
    f32x4 acc1[2][2] = {};
    #pragma unroll
    for (int j = 0; j < 8; ++j) {
      if (A0) {
        #pragma unroll
        for (int cf = 0; cf < 2; ++cf) {
          acc0[cf][0] = __builtin_amdgcn_mfma_f32_16x16x32_f16(a0v[j], l0w[cf][j], acc0[cf][0], 0, 0, 0);
          acc0[cf][1] = __builtin_amdgcn_mfma_f32_16x16x32_f16(a1v[j], l0w[cf][j], acc0[cf][1], 0, 0, 0);
        }
      }
      if (A1) {
        #pragma unroll
        for (int cf = 0; cf < 2; ++cf) {
          acc1[cf][0] = __builtin_amdgcn_mfma_f32_16x16x32_f16(a0v[j], l1aw[cf][j], acc1[cf][0], 0, 0, 0);
          acc1[cf][1] = __builtin_amdgcn_mfma_f32_16x16x32_f16(a1v[j], l1aw[cf][j], acc1[cf][1], 0, 0, 0);
        }
      }
    }
    if (A1) {
      #pragma unroll
      for (int j = 0; j < 8; ++j) {
        #pragma unroll
        for (int cf = 0; cf < 2; ++cf) {
          acc1[cf][0] = __builtin_amdgcn_mfma_f32_16x16x32_f16(c0v[j], l1bw[cf][j], acc1[cf][0], 0, 0, 0);
          acc1[cf][1] = __builtin_amdgcn_mfma_f32_16x16x32_f16(c1v[j], l1bw[cf][j], acc1[cf][1], 0, 0, 0);
        }
      }
    }

    // ---- partial-sum exchange ----
    #pragma unroll
    for (int cf = 0; cf < 2; ++cf)
      #pragma unroll
      for (int rf = 0; rf < 2; ++rf)
        #pragma unroll
        for (int ri = 0; ri < 4; ++ri) {
          if (A0) exc[0][p][rf * 16 + lrq + ri][cf * 16 + lr] = acc0[cf][rf][ri];
          if (A1) exc[1][p][rf * 16 + lrq + ri][cf * 16 + lr] = acc1[cf][rf][ri];
        }
    __syncthreads();

    // ---- cell updates ----
    float hn0 = 0.f, cn0 = 0.f, hn1 = 0.f, cn1 = 0.f;
    if (A0) {
      float gv[4];
      #pragma unroll
      for (int g = 0; g < 4; ++g)
        gv[g] = exc[0][0][crow][g * 8 + cu] + exc[0][1][crow][g * 8 + cu]
              + exc[0][2][crow][g * 8 + cu] + exc[0][3][crow][g * 8 + cu] + pf[g];
      cn0 = sigf(gv[1]) * c0 + sigf(gv[0]) * tanhf_fast(gv[2]);
      hn0 = sigf(gv[3]) * tanhf_fast(cn0);
      c0 = cn0;
      smH[0][crow][cu] = (f16)hn0;
    }
    if (A1) {
      float gv[4];
      #pragma unroll
      for (int g = 0; g < 4; ++g)
        gv[g] = exc[1][0][crow][g * 8 + cu] + exc[1][1][crow][g * 8 + cu]
              + exc[1][2][crow][g * 8 + cu] + exc[1][3][crow][g * 8 + cu] + b1v[g];
      cn1 = sigf(gv[1]) * c1 + sigf(gv[0]) * tanhf_fast(gv[2]);
      hn1 = sigf(gv[3]) * tanhf_fast(cn1);
      c1 = cn1;
      smH[1][crow][cu] = (f16)hn1;
    }
    __syncthreads();

    // ---- publish (wave0: h0, wave1: h1), single drain, flag store ----
    if (A0 && p == 0) {
      const int row = lane >> 1, half = lane & 1;
      ull v = *(const ull*)&smH[0][row][half * 4];
      st_u64g((ull*)(h0r + rt(e) * BH_ + (size_t)(rs + row) * H_ + ub + half * 4), v);
    }
    if (A1 && p == 1) {
      const int row = lane >> 1, half = lane & 1;
      ull v = *(const ull*)&smH[1][row][half * 4];
      st_u64g((ull*)(h1r + rt(e - 1) * BH_ + (size_t)(rs + row) * H_ + ub + half * 4), v);
    }
    asm volatile("s_waitcnt vmcnt(0)" ::: "memory");
    __syncthreads();
    if (tid == 0) st_u32g(&podflags[slot], (unsigned)(e + 1));

    // ---- off-critical-path cached outputs ----
    if (A0 && e == T_ - 1) { outh[cell] = hn0; outc[cell] = cn0; }
    if (A1) {
      out[(size_t)(rs + crow) * (T_ * H_) + (size_t)(e - 1) * H_ + ub + cu] = hn1;
      if (e == T_) { outh[BH_ + cell] = hn1; outc[BH_ + cell] = cn1; }
    }
  };

  body(BC<true>{}, BC<false>{}, 0);
  for (int e = 1; e < T_; ++e) body(BC<true>{}, BC<true>{}, e);
  body(BC<false>{}, BC<true>{}, T_);
}

// ---------------------------------------------------------------------------
extern "C" void kernel_launch(void* const* d_in, const int* in_sizes, int n_in,
                              void* d_out, int out_size, void* d_ws, size_t ws_size,
                              hipStream_t stream)
{
  const float* x    = (const float*)d_in[0];
  const float* h    = (const float*)d_in[1];
  const float* c    = (const float*)d_in[2];
  const float* Wih0 = (const float*)d_in[3];
  const float* Whh0 = (const float*)d_in[4];
  const float* bih0 = (const float*)d_in[5];
  const float* bhh0 = (const float*)d_in[6];
  const float* Wih1 = (const float*)d_in[7];
  const float* Whh1 = (const float*)d_in[8];
  const float* bih1 = (const float*)d_in[9];
  const float* bhh1 = (const float*)d_in[10];

  char* w = (char*)d_ws;
  size_t off = 0;
  auto carve = [&](size_t bytes) -> char* {
    char* ptr = w + off;
    off = (off + bytes + 255) & ~(size_t)255;
    return ptr;
  };
  f16*   pre0T = (f16*)  carve((size_t)T_ * B_ * FH_ * 2);
  f16*   xT    = (f16*)  carve((size_t)T_ * B_ * N_ * 2);
  f16*   wih0  = (f16*)  carve((size_t)FH_ * N_ * 2);
  f16*   whh0  = (f16*)  carve((size_t)FH_ * H_ * 2);
  f16*   wih1  = (f16*)  carve((size_t)FH_ * H_ * 2);
  f16*   whh1  = (f16*)  carve((size_t)FH_ * H_ * 2);
  float* bias0 = (float*)carve((size_t)FH_ * 4);
  float* bias1 = (float*)carve((size_t)FH_ * 4);
  f16*   hinit = (f16*)  carve((size_t)2 * BH_ * 2);
  f16*   h0s   = (f16*)  carve((size_t)8 * BH_ * 2);   // shallow fallback rings
  f16*   h1s   = (f16*)  carve((size_t)8 * BH_ * 2);
  unsigned* flags = (unsigned*)carve(256 * 4);
  const size_t base_end = off;
  f16*   h0ring = (f16*) carve((size_t)T_ * BH_ * 2);  // deep write-once rings
  f16*   h1ring = (f16*) carve((size_t)T_ * BH_ * 2);
  const bool deep = (off <= ws_size);
  if (base_end > ws_size) return;

  init_all<<<2048, 256, 0, stream>>>(x, h, Wih0, bih0, bhh0, Whh0, Wih1, Whh1, bih1, bhh1,
                                     xT, wih0, whh0, wih1, whh1, bias0, bias1, hinit, flags);
  gemm_pre0<<<4096, 256, 0, stream>>>(xT, wih0, bias0, pre0T);
  if (deep)
    lstm_seq<true><<<NWG_SEQ, 256, 0, stream>>>(pre0T, whh0, wih1, whh1, bias1, hinit,
                                                (const float*)c, h0ring, h1ring,
                                                (float*)d_out, flags);
  else
    lstm_seq<false><<<NWG_SEQ, 256, 0, stream>>>(pre0T, whh0, wih1, whh1, bias1, hinit,
                                                 (const float*)c, h0s, h1s,
                                                 (float*)d_out, flags);
}